// Round 8
// baseline (128.750 us; speedup 1.0000x reference)
//
#include <hip/hip_runtime.h>
#include <hip/hip_cooperative_groups.h>
#include <cstdint>

namespace cg = cooperative_groups;

#define GRID_N 4096
#define WPR 64                 // 64-bit words per row
#define NROWS 4096
#define NWORDS (WPR * NROWS)   // 262144 words = 2 MB per buffer

#define KF 16                  // generations per round (2 rounds in coop kernel)
#define OUT 16                 // output rows per block
#define SPAN (OUT + 2 * KF)    // 48 span rows per block
#define RPW (SPAN / 8)         // 6 rows per wave (8 waves/block)
#define NBLK (NROWS / OUT)     // 256 blocks = 1/CU
#define PACK_BLOCKS 2048

// ---------- pack float 0/1 grid -> bitboard + sum(x) partials (proven) ------
__global__ __launch_bounds__(256) void pack_kernel(const float* __restrict__ x,
                                                   uint64_t* __restrict__ bits,
                                                   unsigned long long* __restrict__ px) {
    int lane = threadIdx.x & 63;
    int wv = threadIdx.x >> 6;                 // 0..3
    int gw = blockIdx.x * 4 + wv;              // global wave 0..8191
    unsigned long long pc = 0;
    #pragma unroll
    for (int it = 0; it < 8; ++it) {
        int c = gw * 8 + it;                   // 256-cell chunk
        size_t base = (size_t)c * 256 + lane;
        uint64_t my = 0;
        #pragma unroll
        for (int j = 0; j < 4; ++j) {
            float v = x[base + (size_t)j * 64];    // coalesced 256B/wave
            uint64_t m = __ballot(v > 0.5f);
            if (lane == j) my = m;
        }
        if (lane < 4) {
            bits[(c << 2) + lane] = my;
            pc += (unsigned long long)__popcll(my);
        }
    }
    for (int off = 32; off; off >>= 1) pc += __shfl_down(pc, off, 64);
    __shared__ unsigned long long part[4];
    if (lane == 0) part[wv] = pc;
    __syncthreads();
    if (threadIdx.x == 0)
        px[blockIdx.x] = part[0] + part[1] + part[2] + part[3];
}

// ---------- 32 generations (2 rounds x KF) + sum(y) + finalize, one launch --
__global__ __launch_bounds__(512) void life_kernel(
        const uint64_t* __restrict__ buf0, uint64_t* __restrict__ buf1,
        const unsigned long long* __restrict__ px,
        unsigned long long* __restrict__ py, float* __restrict__ out) {
    cg::grid_group grid = cg::this_grid();
    const int lane = threadIdx.x & 63;
    const int wv = threadIdx.x >> 6;       // 0..7
    const int b = blockIdx.x;
    const int w4 = wv * RPW;               // first span row owned by this wave
    const int gbase = b * OUT - KF;        // global row of span row 0

    __shared__ uint64_t bnd[2][8][2][64];  // [parity][wave][top/bot][lane]
    uint64_t r[RPW];

    for (int round = 0; round < 2; ++round) {
        // load span rows (round 1: only halo rows; valid rows stay in regs)
        const uint64_t* src = (round == 0) ? buf0 : buf1;
        #pragma unroll
        for (int i = 0; i < RPW; ++i) {
            int sr = w4 + i;
            if (round == 0 || sr < KF || sr >= KF + OUT) {
                int gr = gbase + sr;
                r[i] = (gr >= 0 && gr < NROWS) ? src[(size_t)gr * WPR + lane]
                                               : 0ULL;
            }
        }

        #pragma unroll 2
        for (int g = 1; g <= KF; ++g) {
            const int p = g & 1;
            bnd[p][wv][0][lane] = r[0];
            bnd[p][wv][1][lane] = r[RPW - 1];
            __syncthreads();
            uint64_t up = (wv > 0) ? bnd[p][wv - 1][1][lane] : 0ULL;
            uint64_t dn = (wv < 7) ? bnd[p][wv + 1][0][lane] : 0ULL;

            // phase A: vertical column sums (s,c) for all owned rows
            uint64_t sv[RPW], cv[RPW];
            #pragma unroll
            for (int i = 0; i < RPW; ++i) {
                uint64_t a = (i == 0) ? up : r[i - 1];
                uint64_t d = (i == RPW - 1) ? dn : r[i + 1];
                uint64_t m = r[i];
                uint64_t t = a ^ m;
                sv[i] = t ^ d;
                cv[i] = (a & m) | (d & t);
            }

            // one shfl pair for ALL rows' boundary bits
            uint32_t msgL = 0, msgR = 0;
            #pragma unroll
            for (int i = 0; i < RPW; ++i) {
                msgL |= ((uint32_t)(sv[i] >> 63) & 1u) << (2 * i);
                msgL |= ((uint32_t)(cv[i] >> 63) & 1u) << (2 * i + 1);
                msgR |= ((uint32_t)sv[i] & 1u) << (2 * i);
                msgR |= ((uint32_t)cv[i] & 1u) << (2 * i + 1);
            }
            uint32_t fromL = __shfl_up(msgL, 1);
            uint32_t fromR = __shfl_down(msgR, 1);
            fromL = (lane == 0) ? 0u : fromL;
            fromR = (lane == 63) ? 0u : fromR;

            // phase B: horizontal CSA + survival predicate per valid row
            #pragma unroll
            for (int i = 0; i < RPW; ++i) {
                int sr = w4 + i;
                if (sr >= g && sr < SPAN - g) {
                    uint64_t sL = (sv[i] << 1) | (uint64_t)((fromL >> (2 * i)) & 1u);
                    uint64_t cL = (cv[i] << 1) | (uint64_t)((fromL >> (2 * i + 1)) & 1u);
                    uint64_t sR = (sv[i] >> 1) | ((uint64_t)((fromR >> (2 * i)) & 1u) << 63);
                    uint64_t cR = (cv[i] >> 1) | ((uint64_t)((fromR >> (2 * i + 1)) & 1u) << 63);
                    uint64_t t0, t1, u0, u1;
                    { uint64_t tt = sL ^ sv[i]; t0 = tt ^ sR; t1 = (sL & sv[i]) | (sR & tt); }
                    { uint64_t tt = cL ^ cv[i]; u0 = tt ^ cR; u1 = (cL & cv[i]) | (cR & tt); }
                    uint64_t pp = t1 ^ u0, q = t1 & u0;
                    uint64_t pred = (q & u1) | ((q ^ u1) & (pp | t0)); // N8 >= 4
                    r[i] &= pred;
                }
            }
        }

        if (round == 0) {
            // publish the 16 valid rows for next round's halos
            #pragma unroll
            for (int i = 0; i < RPW; ++i) {
                int sr = w4 + i;
                if (sr >= KF && sr < SPAN - KF)
                    buf1[(size_t)(b * OUT + sr - KF) * WPR + lane] = r[i];
            }
            grid.sync();
        }
    }

    // ---- sum(y) partial straight from registers ----
    unsigned long long pc = 0;
    #pragma unroll
    for (int i = 0; i < RPW; ++i) {
        int sr = w4 + i;
        if (sr >= KF && sr < SPAN - KF)
            pc += (unsigned long long)__popcll(r[i]);
    }
    for (int off = 32; off; off >>= 1) pc += __shfl_down(pc, off, 64);
    __shared__ unsigned long long part[8];
    if (lane == 0) part[wv] = pc;
    __syncthreads();
    if (threadIdx.x == 0) {
        unsigned long long s = 0;
        #pragma unroll
        for (int i = 0; i < 8; ++i) s += part[i];
        py[b] = s;
    }

    grid.sync();

    // ---- block 0 finalizes: sum(x) - sum(y) ----
    if (b == 0) {
        int t = threadIdx.x;
        long long v = (long long)px[t] + (long long)px[t + 512] +
                      (long long)px[t + 1024] + (long long)px[t + 1536];
        if (t < NBLK) v -= (long long)py[t];
        for (int off = 32; off; off >>= 1) v += __shfl_down(v, off, 64);
        __shared__ long long fin[8];
        if (lane == 0) fin[wv] = v;
        __syncthreads();
        if (t == 0) {
            long long s = 0;
            #pragma unroll
            for (int i = 0; i < 8; ++i) s += fin[i];
            out[0] = (float)s;             // exact in f32 (|s| <= 2^24)
        }
    }
}

extern "C" void kernel_launch(void* const* d_in, const int* in_sizes, int n_in,
                              void* d_out, int out_size, void* d_ws, size_t ws_size,
                              hipStream_t stream) {
    const float* x = (const float*)d_in[0];
    float* out = (float*)d_out;

    uint8_t* ws = (uint8_t*)d_ws;
    uint64_t* buf0 = (uint64_t*)ws;                               // 2 MB
    uint64_t* buf1 = (uint64_t*)(ws + (size_t)NWORDS * 8);        // 2 MB
    unsigned long long* px = (unsigned long long*)(ws + (size_t)2 * NWORDS * 8); // 2048
    unsigned long long* py = px + PACK_BLOCKS;                                   // 256

    // 2 dispatches total
    pack_kernel<<<PACK_BLOCKS, 256, 0, stream>>>(x, buf0, px);

    void* args[] = { (void*)&buf0, (void*)&buf1, (void*)&px, (void*)&py, (void*)&out };
    hipLaunchCooperativeKernel(reinterpret_cast<void*>(life_kernel),
                               dim3(NBLK), dim3(512), args, 0, stream);
}

// Round 9
// 101.067 us; speedup vs baseline: 1.2739x; 1.2739x over previous
//
#include <hip/hip_runtime.h>
#include <cstdint>

#define WPR 64                 // 64-bit words per row
#define NROWS 4096
#define NWORDS (WPR * NROWS)   // 2 MB board

#define KF 32                  // ALL generations fused in one dispatch
#define OUT 16                 // output rows per block
#define SPAN (OUT + 2 * KF)    // 80 span rows per block
#define RPW (SPAN / 8)         // 10 rows per wave (8 waves/block)
#define NBLK (NROWS / OUT)     // 256 blocks = 1/CU
#define PACK_BLOCKS 2048

// ---------- pack float 0/1 grid -> bitboard + sum(x) partials; zero ticket --
__global__ __launch_bounds__(256) void pack_kernel(const float* __restrict__ x,
                                                   uint64_t* __restrict__ bits,
                                                   unsigned long long* __restrict__ px,
                                                   unsigned int* __restrict__ done) {
    int lane = threadIdx.x & 63;
    int wv = threadIdx.x >> 6;                 // 0..3
    int gw = blockIdx.x * 4 + wv;              // global wave 0..8191
    unsigned long long pc = 0;
    #pragma unroll
    for (int it = 0; it < 8; ++it) {
        int c = gw * 8 + it;                   // 256-cell chunk
        size_t base = (size_t)c * 256 + lane;
        uint64_t my = 0;
        #pragma unroll
        for (int j = 0; j < 4; ++j) {
            float v = x[base + (size_t)j * 64];    // coalesced 256B/wave
            uint64_t m = __ballot(v > 0.5f);
            if (lane == j) my = m;
        }
        if (lane < 4) {
            bits[(c << 2) + lane] = my;
            pc += (unsigned long long)__popcll(my);
        }
    }
    for (int off = 32; off; off >>= 1) pc += __shfl_down(pc, off, 64);
    __shared__ unsigned long long part[4];
    if (lane == 0) part[wv] = pc;
    __syncthreads();
    if (threadIdx.x == 0)
        px[blockIdx.x] = part[0] + part[1] + part[2] + part[3];
    if (blockIdx.x == 0 && threadIdx.x == 0)
        *done = 0u;                            // reset ticket every launch
}

// ---------- 32 generations in one dispatch + sum(y) + ticket finalize ------
__global__ __launch_bounds__(512) void life32_kernel(
        const uint64_t* __restrict__ in,
        const unsigned long long* __restrict__ px,
        unsigned long long* __restrict__ py,
        unsigned int* __restrict__ done, float* __restrict__ out) {
    const int lane = threadIdx.x & 63;
    const int wv = threadIdx.x >> 6;       // 0..7
    const int b = blockIdx.x;
    const int w4 = wv * RPW;               // first span row owned by this wave
    const int gbase = b * OUT - KF;        // global row of span row 0

    uint64_t r[RPW];
    #pragma unroll
    for (int i = 0; i < RPW; ++i) {
        int gr = gbase + w4 + i;
        r[i] = (gr >= 0 && gr < NROWS) ? in[(size_t)gr * WPR + lane] : 0ULL;
    }

    __shared__ uint64_t bnd[2][8][2][64];  // [parity][wave][top/bot][lane]

    #pragma unroll 2
    for (int g = 1; g <= KF; ++g) {
        const int p = g & 1;
        bnd[p][wv][0][lane] = r[0];
        bnd[p][wv][1][lane] = r[RPW - 1];
        __syncthreads();
        uint64_t up = (wv > 0) ? bnd[p][wv - 1][1][lane] : 0ULL;
        uint64_t dn = (wv < 7) ? bnd[p][wv + 1][0][lane] : 0ULL;

        // phase A: vertical column sums for rows in the valid pyramid only
        // (guards are wave-uniform -> whole-row s_cbranch skips)
        uint64_t sv[RPW], cv[RPW];
        #pragma unroll
        for (int i = 0; i < RPW; ++i) {
            int sr = w4 + i;
            if (sr >= g && sr < SPAN - g) {
                uint64_t a = (i == 0) ? up : r[i - 1];
                uint64_t d = (i == RPW - 1) ? dn : r[i + 1];
                uint64_t m = r[i];
                uint64_t t = a ^ m;
                sv[i] = t ^ d;
                cv[i] = (a & m) | (d & t);
            } else {
                sv[i] = 0; cv[i] = 0;
            }
        }

        // one shfl pair for ALL rows' boundary bits (2 bits per row per dir)
        uint32_t msgL = 0, msgR = 0;
        #pragma unroll
        for (int i = 0; i < RPW; ++i) {
            msgL |= ((uint32_t)(sv[i] >> 63) & 1u) << (2 * i);
            msgL |= ((uint32_t)(cv[i] >> 63) & 1u) << (2 * i + 1);
            msgR |= ((uint32_t)sv[i] & 1u) << (2 * i);
            msgR |= ((uint32_t)cv[i] & 1u) << (2 * i + 1);
        }
        uint32_t fromL = __shfl_up(msgL, 1);
        uint32_t fromR = __shfl_down(msgR, 1);
        fromL = (lane == 0) ? 0u : fromL;
        fromR = (lane == 63) ? 0u : fromR;

        // phase B: horizontal CSA + survival predicate per valid row
        #pragma unroll
        for (int i = 0; i < RPW; ++i) {
            int sr = w4 + i;
            if (sr >= g && sr < SPAN - g) {
                uint64_t sL = (sv[i] << 1) | (uint64_t)((fromL >> (2 * i)) & 1u);
                uint64_t cL = (cv[i] << 1) | (uint64_t)((fromL >> (2 * i + 1)) & 1u);
                uint64_t sR = (sv[i] >> 1) | ((uint64_t)((fromR >> (2 * i)) & 1u) << 63);
                uint64_t cR = (cv[i] >> 1) | ((uint64_t)((fromR >> (2 * i + 1)) & 1u) << 63);
                uint64_t t0, t1, u0, u1;
                { uint64_t tt = sL ^ sv[i]; t0 = tt ^ sR; t1 = (sL & sv[i]) | (sR & tt); }
                { uint64_t tt = cL ^ cv[i]; u0 = tt ^ cR; u1 = (cL & cv[i]) | (cR & tt); }
                uint64_t pp = t1 ^ u0, q = t1 & u0;
                uint64_t pred = (q & u1) | ((q ^ u1) & (pp | t0)); // N8 >= 4
                r[i] &= pred;
            }
        }
    }

    // ---- sum(y) partial straight from registers (no board store at all) ----
    unsigned long long pc = 0;
    #pragma unroll
    for (int i = 0; i < RPW; ++i) {
        int sr = w4 + i;
        if (sr >= KF && sr < SPAN - KF)
            pc += (unsigned long long)__popcll(r[i]);
    }
    for (int off = 32; off; off >>= 1) pc += __shfl_down(pc, off, 64);
    __shared__ unsigned long long part[8];
    __shared__ unsigned int ticket_s;
    __shared__ long long fin[8];
    if (lane == 0) part[wv] = pc;
    __syncthreads();
    if (threadIdx.x == 0) {
        unsigned long long s = 0;
        #pragma unroll
        for (int i = 0; i < 8; ++i) s += part[i];
        py[b] = s;
        __threadfence();                   // release partial before ticket
        ticket_s = atomicAdd(done, 1u);
    }
    __syncthreads();

    // ---- last-arriving block finalizes sum(x) - sum(y) ----
    if (ticket_s == NBLK - 1) {
        __threadfence();                   // acquire all blocks' partials
        int t = threadIdx.x;
        long long v = (long long)px[t] + (long long)px[t + 512] +
                      (long long)px[t + 1024] + (long long)px[t + 1536];
        if (t < NBLK) v -= (long long)py[t];
        for (int off = 32; off; off >>= 1) v += __shfl_down(v, off, 64);
        if (lane == 0) fin[wv] = v;
        __syncthreads();
        if (t == 0) {
            long long s = 0;
            #pragma unroll
            for (int i = 0; i < 8; ++i) s += fin[i];
            out[0] = (float)s;             // exact in f32 (|s| <= 2^24)
        }
    }
}

extern "C" void kernel_launch(void* const* d_in, const int* in_sizes, int n_in,
                              void* d_out, int out_size, void* d_ws, size_t ws_size,
                              hipStream_t stream) {
    const float* x = (const float*)d_in[0];
    float* out = (float*)d_out;

    uint8_t* ws = (uint8_t*)d_ws;
    uint64_t* buf0 = (uint64_t*)ws;                                   // 2 MB
    unsigned long long* px = (unsigned long long*)(ws + (size_t)NWORDS * 8); // 2048
    unsigned long long* py = px + PACK_BLOCKS;                               // 256
    unsigned int* done = (unsigned int*)(py + NBLK);

    // 2 dispatches, no memset, no cooperative launch, no grid.sync
    pack_kernel<<<PACK_BLOCKS, 256, 0, stream>>>(x, buf0, px, done);
    life32_kernel<<<NBLK, 512, 0, stream>>>(buf0, px, py, done, out);
}

// Round 10
// 67.599 us; speedup vs baseline: 1.9046x; 1.4951x over previous
//
#include <hip/hip_runtime.h>
#include <cstdint>

#define WPR 64                 // 64-bit words per row
#define NROWS 4096
#define NWORDS (WPR * NROWS)   // 2 MB board

#define KF 16                  // generations per step dispatch (x2 dispatches)
#define OUT 16                 // output rows per block
#define SPAN (OUT + 2 * KF)    // 48 span rows per block
#define NWAVES 16              // 1024 threads
#define RPW (SPAN / NWAVES)    // 3 rows per wave, STRIDED by NWAVES
#define NBLK (NROWS / OUT)     // 256 blocks = 1/CU
#define PACK_BLOCKS 2048

// ---------- pack float 0/1 grid -> bitboard + sum(x) partials; reset ticket -
__global__ __launch_bounds__(256) void pack_kernel(const float* __restrict__ x,
                                                   uint64_t* __restrict__ bits,
                                                   unsigned long long* __restrict__ px,
                                                   unsigned int* __restrict__ done) {
    int lane = threadIdx.x & 63;
    int wv = threadIdx.x >> 6;                 // 0..3
    int gw = blockIdx.x * 4 + wv;              // global wave 0..8191
    unsigned long long pc = 0;
    #pragma unroll
    for (int it = 0; it < 8; ++it) {
        int c = gw * 8 + it;                   // 256-cell chunk
        size_t base = (size_t)c * 256 + lane;
        uint64_t my = 0;
        #pragma unroll
        for (int j = 0; j < 4; ++j) {
            float v = x[base + (size_t)j * 64];    // coalesced 256B/wave
            uint64_t m = __ballot(v > 0.5f);
            if (lane == j) my = m;
        }
        if (lane < 4) {
            bits[(c << 2) + lane] = my;
            pc += (unsigned long long)__popcll(my);
        }
    }
    for (int off = 32; off; off >>= 1) pc += __shfl_down(pc, off, 64);
    __shared__ unsigned long long part[4];
    if (lane == 0) part[wv] = pc;
    __syncthreads();
    if (threadIdx.x == 0)
        px[blockIdx.x] = part[0] + part[1] + part[2] + part[3];
    if (blockIdx.x == 0 && threadIdx.x == 0)
        *done = 0u;                            // reset ticket every launch
}

// ---------- KF gens; strided row ownership + LDS slab (balanced pyramid) ----
template <bool FINAL>
__global__ __launch_bounds__(1024) void step_kernel(
        const uint64_t* __restrict__ in, uint64_t* __restrict__ out,
        const unsigned long long* __restrict__ px,
        unsigned long long* __restrict__ py,
        unsigned int* __restrict__ done, float* __restrict__ res) {
    const int lane = threadIdx.x & 63;
    const int wv = threadIdx.x >> 6;       // 0..15
    const int b = blockIdx.x;
    const int gbase = b * OUT - KF;        // global row of span row 0

    __shared__ uint64_t lds[2][SPAN][64];  // double-buffered slab, 48 KB

    // load strided rows: wave wv owns span rows wv, wv+16, wv+32
    uint64_t r[RPW];
    #pragma unroll
    for (int i = 0; i < RPW; ++i) {
        int sr = wv + NWAVES * i;
        int gr = gbase + sr;
        uint64_t v = (gr >= 0 && gr < NROWS) ? in[(size_t)gr * WPR + lane] : 0ULL;
        r[i] = v;
        lds[0][sr][lane] = v;
    }
    __syncthreads();

    #pragma unroll
    for (int g = 1; g <= KF; ++g) {
        const int rp = (g - 1) & 1, wp = g & 1;

        // phase A: vertical column sums; neighbors from LDS (balanced rows)
        uint64_t sv[RPW], cv[RPW];
        #pragma unroll
        for (int i = 0; i < RPW; ++i) {
            int sr = wv + NWAVES * i;
            if (sr >= g && sr < SPAN - g) {        // wave-uniform guard
                uint64_t up = lds[rp][sr - 1][lane];
                uint64_t dn = lds[rp][sr + 1][lane];
                uint64_t m = r[i];
                uint64_t t = up ^ m;
                sv[i] = t ^ dn;
                cv[i] = (up & m) | (dn & t);
            } else { sv[i] = 0; cv[i] = 0; }
        }

        // one shfl pair for ALL rows' boundary bits (2 bits per row per dir)
        uint32_t msgL = 0, msgR = 0;
        #pragma unroll
        for (int i = 0; i < RPW; ++i) {
            msgL |= ((uint32_t)(sv[i] >> 63) & 1u) << (2 * i);
            msgL |= ((uint32_t)(cv[i] >> 63) & 1u) << (2 * i + 1);
            msgR |= ((uint32_t)sv[i] & 1u) << (2 * i);
            msgR |= ((uint32_t)cv[i] & 1u) << (2 * i + 1);
        }
        uint32_t fromL = __shfl_up(msgL, 1);
        uint32_t fromR = __shfl_down(msgR, 1);
        fromL = (lane == 0) ? 0u : fromL;
        fromR = (lane == 63) ? 0u : fromR;

        // phase B: horizontal CSA + survival; write new value to other buffer
        #pragma unroll
        for (int i = 0; i < RPW; ++i) {
            int sr = wv + NWAVES * i;
            if (sr >= g && sr < SPAN - g) {
                uint64_t sL = (sv[i] << 1) | (uint64_t)((fromL >> (2 * i)) & 1u);
                uint64_t cL = (cv[i] << 1) | (uint64_t)((fromL >> (2 * i + 1)) & 1u);
                uint64_t sR = (sv[i] >> 1) | ((uint64_t)((fromR >> (2 * i)) & 1u) << 63);
                uint64_t cR = (cv[i] >> 1) | ((uint64_t)((fromR >> (2 * i + 1)) & 1u) << 63);
                uint64_t t0, t1, u0, u1;
                { uint64_t tt = sL ^ sv[i]; t0 = tt ^ sR; t1 = (sL & sv[i]) | (sR & tt); }
                { uint64_t tt = cL ^ cv[i]; u0 = tt ^ cR; u1 = (cL & cv[i]) | (cR & tt); }
                uint64_t pp = t1 ^ u0, q = t1 & u0;
                uint64_t pred = (q & u1) | ((q ^ u1) & (pp | t0)); // N8 >= 4
                r[i] &= pred;
                lds[wp][sr][lane] = r[i];
            }
        }
        __syncthreads();   // one barrier/gen: writes visible before next reads
    }

    // valid rows [KF, KF+OUT) = [16,32): exactly i==1 (sr = wv+16) per wave
    if (!FINAL) {
        out[(size_t)(b * OUT + wv) * WPR + lane] = r[1];
    } else {
        // sum(y) partial straight from registers; no final board store
        unsigned long long pc = (unsigned long long)__popcll(r[1]);
        for (int off = 32; off; off >>= 1) pc += __shfl_down(pc, off, 64);
        __shared__ unsigned long long part[NWAVES];
        __shared__ unsigned int ticket_s;
        __shared__ long long fin[NWAVES];
        if (lane == 0) part[wv] = pc;
        __syncthreads();
        if (threadIdx.x == 0) {
            unsigned long long s = 0;
            #pragma unroll
            for (int i = 0; i < NWAVES; ++i) s += part[i];
            py[b] = s;
            __threadfence();               // release partial before ticket
            ticket_s = atomicAdd(done, 1u);
        }
        __syncthreads();
        if (ticket_s == NBLK - 1) {        // last-arriving block finalizes
            __threadfence();               // acquire all blocks' partials
            int t = threadIdx.x;
            long long v = (long long)px[t] + (long long)px[t + 1024];
            if (t < NBLK) v -= (long long)py[t];
            for (int off = 32; off; off >>= 1) v += __shfl_down(v, off, 64);
            if (lane == 0) fin[wv] = v;
            __syncthreads();
            if (t == 0) {
                long long s = 0;
                #pragma unroll
                for (int i = 0; i < NWAVES; ++i) s += fin[i];
                res[0] = (float)s;         // exact in f32 (|s| <= 2^24)
            }
        }
    }
}

extern "C" void kernel_launch(void* const* d_in, const int* in_sizes, int n_in,
                              void* d_out, int out_size, void* d_ws, size_t ws_size,
                              hipStream_t stream) {
    const float* x = (const float*)d_in[0];
    float* out = (float*)d_out;

    uint8_t* ws = (uint8_t*)d_ws;
    uint64_t* buf0 = (uint64_t*)ws;                                   // 2 MB
    uint64_t* buf1 = (uint64_t*)(ws + (size_t)NWORDS * 8);            // 2 MB
    unsigned long long* px = (unsigned long long*)(ws + (size_t)2 * NWORDS * 8); // 2048
    unsigned long long* py = px + PACK_BLOCKS;                               // 256
    unsigned int* done = (unsigned int*)(py + NBLK);

    // 3 dispatches, no memset, no grid.sync
    pack_kernel<<<PACK_BLOCKS, 256, 0, stream>>>(x, buf0, px, done);
    step_kernel<false><<<NBLK, 1024, 0, stream>>>(buf0, buf1, nullptr, nullptr, nullptr, nullptr);
    step_kernel<true ><<<NBLK, 1024, 0, stream>>>(buf1, nullptr, px, py, done, out);
}